// Round 13
// baseline (108.920 us; speedup 1.0000x reference)
//
#include <hip/hip_runtime.h>

namespace {

constexpr int K     = 6;
constexpr int KK    = 36;   // K*K
constexpr int DF    = 8;    // D_FEAT
constexpr int DLAT  = 16;
constexpr int NS    = 5;
constexpr int B     = 131072;
constexpr int M     = NS * B;
constexpr float EPS = 1e-20f;

// grid = 2560 blocks of 256; bid -> (s = bid%5, bc = bid/5): the 5 blocks
// sharing a b-range are dispatch-adjacent (latent/seq L3/L2-hot) and each
// wave's 64 noise/out rows are CONTIGUOUS (144 B and 192 B rows -> perfect
// line assembly in L2 for both streams).
// No LDS (round 12's 53 KB capped occupancy at 3 blocks/CU = 28.9%), no NT
// hints (round 10: NT 16-B stores amplify 3x; round 11: NT loads forfeit L3
// reuse, +28 us). Plain cached float4 everywhere; occupancy becomes
// VGPR-limited (~72 regs -> ~7 waves/SIMD) for max loads-in-flight.
__global__ __launch_bounds__(256) void fused_kernel(
    const float* __restrict__ latent,
    const float* __restrict__ seq,
    const float* __restrict__ noise,
    const float* __restrict__ W_sink,
    const float* __restrict__ b_sink,
    const float* __restrict__ W_mask,
    const float* __restrict__ b_mask,
    float* __restrict__ out,        // [NS*B][48]
    float* __restrict__ stopping)   // [B][6]
{
    const int bid = blockIdx.x;
    const int s   = bid % NS;
    const int bc  = bid / NS;
    const int t   = threadIdx.x;
    const int b   = bc * 256 + t;
    const size_t row = (size_t)s * B + b;

    // ---- noise row (144 B, wave-contiguous), cached ----
    float u[KK];
    {
        const float4* n4 = reinterpret_cast<const float4*>(noise + row * KK);
        #pragma unroll
        for (int q = 0; q < 9; ++q) {
            float4 v = n4[q];
            u[q*4+0] = v.x; u[q*4+1] = v.y; u[q*4+2] = v.z; u[q*4+3] = v.w;
        }
    }

    // ---- latent + sinknet matvec (W/b wave-uniform -> scalar loads) ----
    float lat[DLAT];
    {
        const float4* lat4 = reinterpret_cast<const float4*>(latent + (size_t)b * DLAT);
        #pragma unroll
        for (int k2 = 0; k2 < 4; ++k2) {
            float4 v = lat4[k2];
            lat[k2*4+0] = v.x; lat[k2*4+1] = v.y; lat[k2*4+2] = v.z; lat[k2*4+3] = v.w;
        }
    }

    float ela[KK];
    #pragma unroll
    for (int i = 0; i < KK; ++i) ela[i] = b_sink[i];
    #pragma unroll
    for (int k2 = 0; k2 < DLAT; ++k2) {
        const float lv = lat[k2];
        #pragma unroll
        for (int i = 0; i < KK; ++i)
            ela[i] = fmaf(lv, W_sink[k2*KK + i], ela[i]);
    }

    if (s == 0) {   // masknet once per b
        float v[K];
        #pragma unroll
        for (int i = 0; i < K; ++i) v[i] = b_mask[i];
        #pragma unroll
        for (int k2 = 0; k2 < DLAT; ++k2) {
            const float lv = lat[k2];
            #pragma unroll
            for (int i = 0; i < K; ++i)
                v[i] = fmaf(lv, W_mask[k2*K + i], v[i]);
        }
        float mx = v[0];
        #pragma unroll
        for (int i = 1; i < K; ++i) mx = fmaxf(mx, v[i]);
        float sum = 0.f;
        #pragma unroll
        for (int i = 0; i < K; ++i) { v[i] = __expf(v[i] - mx); sum += v[i]; }
        const float inv = __builtin_amdgcn_rcpf(sum);
        float2* o2 = reinterpret_cast<float2*>(stopping + (size_t)b * K);
        o2[0] = make_float2(v[0]*inv, v[1]*inv);
        o2[1] = make_float2(v[2]*inv, v[3]*inv);
        o2[2] = make_float2(v[4]*inv, v[5]*inv);
    }

    // ---- p = exp(la) * rcp(EPS - log(u+EPS))  (== exp(la + gumbel)) ----
    float p[KK];
    #pragma unroll
    for (int i = 0; i < KK; ++i)
        p[i] = __expf(ela[i]) * __builtin_amdgcn_rcpf(EPS - __logf(u[i] + EPS));

    // ---- 5 Sinkhorn iterations, exp domain (== log-domain logsumexp) ----
    #pragma unroll
    for (int it = 0; it < 5; ++it) {
        #pragma unroll
        for (int i = 0; i < K; ++i) {            // rows (axis=2)
            const float sum = ((p[i*K+0] + p[i*K+1]) + (p[i*K+2] + p[i*K+3]))
                            + (p[i*K+4] + p[i*K+5]);
            const float r = __builtin_amdgcn_rcpf(sum);
            #pragma unroll
            for (int j = 0; j < K; ++j) p[i*K+j] *= r;
        }
        #pragma unroll
        for (int j = 0; j < K; ++j) {            // cols (axis=1)
            const float sum = ((p[0*K+j] + p[1*K+j]) + (p[2*K+j] + p[3*K+j]))
                            + (p[4*K+j] + p[5*K+j]);
            const float r = __builtin_amdgcn_rcpf(sum);
            #pragma unroll
            for (int i = 0; i < K; ++i) p[i*K+j] *= r;
        }
    }

    // ---- ordered[row,i,:] = sum_j P[j,i] * seq[b,j,:] ----
    float o[K*DF];
    #pragma unroll
    for (int i = 0; i < K*DF; ++i) o[i] = 0.f;

    const float4* s4 = reinterpret_cast<const float4*>(seq + (size_t)b * (K*DF));
    #pragma unroll
    for (int j = 0; j < K; ++j) {
        float4 a0 = s4[j*2 + 0];
        float4 a1 = s4[j*2 + 1];
        float srow[DF] = {a0.x, a0.y, a0.z, a0.w, a1.x, a1.y, a1.z, a1.w};
        #pragma unroll
        for (int i = 0; i < K; ++i) {
            const float pv = p[j*K + i];
            #pragma unroll
            for (int d = 0; d < DF; ++d)
                o[i*DF + d] = fmaf(pv, srow[d], o[i*DF + d]);
        }
    }

    // ---- plain cached stores; wave rows contiguous -> L2 assembles lines ----
    float4* o4 = reinterpret_cast<float4*>(out + row * (K*DF));
    #pragma unroll
    for (int q = 0; q < 12; ++q) {
        float4 v;
        v.x = o[q*4+0]; v.y = o[q*4+1]; v.z = o[q*4+2]; v.w = o[q*4+3];
        o4[q] = v;
    }
}

} // namespace

extern "C" void kernel_launch(void* const* d_in, const int* in_sizes, int n_in,
                              void* d_out, int out_size, void* d_ws, size_t ws_size,
                              hipStream_t stream) {
    const float* latent = (const float*)d_in[0];
    const float* seq    = (const float*)d_in[1];
    const float* noise  = (const float*)d_in[2];
    const float* W_sink = (const float*)d_in[3];
    const float* b_sink = (const float*)d_in[4];
    const float* W_mask = (const float*)d_in[5];
    const float* b_mask = (const float*)d_in[6];
    float* out      = (float*)d_out;
    float* stopping = out + (size_t)M * K * DF;

    fused_kernel<<<M / 256, 256, 0, stream>>>(latent, seq, noise,
                                              W_sink, b_sink, W_mask, b_mask,
                                              out, stopping);
}

// Round 14
// 91.553 us; speedup vs baseline: 1.1897x; 1.1897x over previous
//
#include <hip/hip_runtime.h>

namespace {

constexpr int K     = 6;
constexpr int KK    = 36;   // K*K
constexpr int DF    = 8;    // D_FEAT
constexpr int DLAT  = 16;
constexpr int NS    = 5;
constexpr int B     = 131072;
constexpr int M     = NS * B;
constexpr float EPS = 1e-20f;

// Round-5 structure (proven lowest HBM traffic: steady FETCH 74.5 MB):
// one thread per (s,b), BATCH-MAJOR (b = m/5): the 5 samples of one b sit in
// adjacent lanes -> latent/seq fetched once per wave (L1 broadcast), no
// cross-block reuse needed, so the write stream can't evict anything useful.
// Round-14 changes, all latency-targeted:
//  * load schedule: latent first, then noise burst; matvec waits only on
//    latent (vmcnt in-order) while noise flies; seq burst issued right after
//    matvec so gumbel+sinkhorn (~2000 cyc) cover it. One exposure per wave.
//  * masknet fused into s==0 lanes (kills 2nd launch + 8 MB latent re-read).
//  * plain cached loads/stores only (r10: NT 16-B stores amplify 3x;
//    r11: NT loads forfeit L3 reuse).
__global__ __launch_bounds__(256) void fused_kernel(
    const float* __restrict__ latent,
    const float* __restrict__ seq,
    const float* __restrict__ noise,
    const float* __restrict__ W_sink,
    const float* __restrict__ b_sink,
    const float* __restrict__ W_mask,
    const float* __restrict__ b_mask,
    float* __restrict__ out,        // [NS*B][48]
    float* __restrict__ stopping)   // [B][6]
{
    const int m = blockIdx.x * 256 + threadIdx.x;
    const int b = (int)((unsigned)m / 5u);
    const int s = m - b * 5;
    const size_t row = (size_t)s * B + b;

    // ---- 1) latent loads (first: matvec's wait leaves the rest in flight) --
    const float4* lat4 = reinterpret_cast<const float4*>(latent + (size_t)b * DLAT);
    float4 l0 = lat4[0], l1 = lat4[1], l2 = lat4[2], l3 = lat4[3];

    // ---- 2) noise burst (9x16B, in flight across matvec) ----
    const float4* n4 = reinterpret_cast<const float4*>(noise + row * KK);
    float4 nv[9];
    #pragma unroll
    for (int q = 0; q < 9; ++q) nv[q] = n4[q];

    float lat[DLAT] = {l0.x, l0.y, l0.z, l0.w, l1.x, l1.y, l1.z, l1.w,
                       l2.x, l2.y, l2.z, l2.w, l3.x, l3.y, l3.z, l3.w};

    // ---- matvec (576 FMA ~ covers noise latency); W/b -> scalar loads ----
    float ela[KK];
    #pragma unroll
    for (int i = 0; i < KK; ++i) ela[i] = b_sink[i];
    #pragma unroll
    for (int k2 = 0; k2 < DLAT; ++k2) {
        const float lv = lat[k2];
        #pragma unroll
        for (int i = 0; i < KK; ++i)
            ela[i] = fmaf(lv, W_sink[k2*KK + i], ela[i]);
    }

    // ---- 3) seq burst (12x16B; gumbel+sinkhorn ~2000 cyc cover it) ----
    const float4* s4 = reinterpret_cast<const float4*>(seq + (size_t)b * (K*DF));
    float4 sv[12];
    #pragma unroll
    for (int q = 0; q < 12; ++q) sv[q] = s4[q];

    // ---- masknet on s==0 lanes (predicated; adds noise-load cover) ----
    if (s == 0) {
        float v[K];
        #pragma unroll
        for (int i = 0; i < K; ++i) v[i] = b_mask[i];
        #pragma unroll
        for (int k2 = 0; k2 < DLAT; ++k2) {
            const float lv = lat[k2];
            #pragma unroll
            for (int i = 0; i < K; ++i)
                v[i] = fmaf(lv, W_mask[k2*K + i], v[i]);
        }
        float mx = v[0];
        #pragma unroll
        for (int i = 1; i < K; ++i) mx = fmaxf(mx, v[i]);
        float sum = 0.f;
        #pragma unroll
        for (int i = 0; i < K; ++i) { v[i] = __expf(v[i] - mx); sum += v[i]; }
        const float inv = __builtin_amdgcn_rcpf(sum);
        float2* o2 = reinterpret_cast<float2*>(stopping + (size_t)b * K);
        o2[0] = make_float2(v[0]*inv, v[1]*inv);
        o2[1] = make_float2(v[2]*inv, v[3]*inv);
        o2[2] = make_float2(v[4]*inv, v[5]*inv);
    }

    // ---- exp(la); then gumbel in place: p = ela * rcp(EPS - log(u+EPS)) ----
    #pragma unroll
    for (int i = 0; i < KK; ++i) ela[i] = __expf(ela[i]);

    float p[KK];
    #pragma unroll
    for (int q = 0; q < 9; ++q) {
        float4 u = nv[q];
        p[q*4+0] = ela[q*4+0] * __builtin_amdgcn_rcpf(EPS - __logf(u.x + EPS));
        p[q*4+1] = ela[q*4+1] * __builtin_amdgcn_rcpf(EPS - __logf(u.y + EPS));
        p[q*4+2] = ela[q*4+2] * __builtin_amdgcn_rcpf(EPS - __logf(u.z + EPS));
        p[q*4+3] = ela[q*4+3] * __builtin_amdgcn_rcpf(EPS - __logf(u.w + EPS));
    }

    // ---- 5 Sinkhorn iterations, exp domain (== log-domain logsumexp) ----
    #pragma unroll
    for (int it = 0; it < 5; ++it) {
        #pragma unroll
        for (int i = 0; i < K; ++i) {            // rows (axis=2)
            const float sum = ((p[i*K+0] + p[i*K+1]) + (p[i*K+2] + p[i*K+3]))
                            + (p[i*K+4] + p[i*K+5]);
            const float r = __builtin_amdgcn_rcpf(sum);
            #pragma unroll
            for (int j = 0; j < K; ++j) p[i*K+j] *= r;
        }
        #pragma unroll
        for (int j = 0; j < K; ++j) {            // cols (axis=1)
            const float sum = ((p[0*K+j] + p[1*K+j]) + (p[2*K+j] + p[3*K+j]))
                            + (p[4*K+j] + p[5*K+j]);
            const float r = __builtin_amdgcn_rcpf(sum);
            #pragma unroll
            for (int i = 0; i < K; ++i) p[i*K+j] *= r;
        }
    }

    // ---- ordered[row,i,:] = sum_j P[j,i] * seq[b,j,:]  (seq in sv regs) ----
    float o[K*DF];
    #pragma unroll
    for (int i = 0; i < K*DF; ++i) o[i] = 0.f;
    #pragma unroll
    for (int j = 0; j < K; ++j) {
        const float srow[DF] = {sv[j*2].x, sv[j*2].y, sv[j*2].z, sv[j*2].w,
                                sv[j*2+1].x, sv[j*2+1].y, sv[j*2+1].z, sv[j*2+1].w};
        #pragma unroll
        for (int i = 0; i < K; ++i) {
            const float pv = p[j*K + i];
            #pragma unroll
            for (int d = 0; d < DF; ++d)
                o[i*DF + d] = fmaf(pv, srow[d], o[i*DF + d]);
        }
    }

    float4* o4 = reinterpret_cast<float4*>(out + row * (K*DF));
    #pragma unroll
    for (int q = 0; q < 12; ++q) {
        float4 v;
        v.x = o[q*4+0]; v.y = o[q*4+1]; v.z = o[q*4+2]; v.w = o[q*4+3];
        o4[q] = v;
    }
}

} // namespace

extern "C" void kernel_launch(void* const* d_in, const int* in_sizes, int n_in,
                              void* d_out, int out_size, void* d_ws, size_t ws_size,
                              hipStream_t stream) {
    const float* latent = (const float*)d_in[0];
    const float* seq    = (const float*)d_in[1];
    const float* noise  = (const float*)d_in[2];
    const float* W_sink = (const float*)d_in[3];
    const float* b_sink = (const float*)d_in[4];
    const float* W_mask = (const float*)d_in[5];
    const float* b_mask = (const float*)d_in[6];
    float* out      = (float*)d_out;
    float* stopping = out + (size_t)M * K * DF;

    fused_kernel<<<M / 256, 256, 0, stream>>>(latent, seq, noise,
                                              W_sink, b_sink, W_mask, b_mask,
                                              out, stopping);
}